// Round 3
// baseline (729.176 us; speedup 1.0000x reference)
//
#include <hip/hip_runtime.h>
#include <hip/hip_bf16.h>
#include <stdint.h>

#define L 1024
#define D 1024
#define NLAYER 4
#define NSTATE 16
#define DI 2048
#define DTR 64
#define KCONV 4
#define XD 96      // DTR + 2*NSTATE
#define NC 64      // scan chunks
#define CT 16      // timesteps per chunk (L/NC)
#define KSPLIT 16  // x_proj split-K

typedef __attribute__((ext_vector_type(8))) short short8;
typedef __attribute__((ext_vector_type(4))) float floatx4;

__device__ __forceinline__ float siluf(float x) { return x / (1.f + __expf(-x)); }

__device__ __forceinline__ unsigned short f2bf(float x) {
    __hip_bfloat16 b = __float2bfloat16(x);
    return *reinterpret_cast<unsigned short*>(&b);
}

#ifndef __has_builtin
#define __has_builtin(x) 0
#endif
#if __has_builtin(__builtin_amdgcn_global_load_lds)
#define HAVE_GLD 1
#define GLD(gp, lp) __builtin_amdgcn_global_load_lds(                                  \
    (const __attribute__((address_space(1))) void*)(gp),                               \
    (__attribute__((address_space(3))) void*)(lp), 16, 0, 0)
#endif

// ---------------- all-layer weight fp32->bf16 conversion (1 launch) ----------------
#define N_IN4  1048576   // 4096*1024/4
#define N_XP4  49152     // 96*2048/4
#define N_DT4  32768     // 2048*64/4
#define N_OUT4 524288    // 1024*2048/4
#define N_CVT4 (N_IN4 + N_XP4 + N_DT4 + N_OUT4)

__global__ __launch_bounds__(256) void cvt_all_kernel(
    const float* __restrict__ in_w, const float* __restrict__ xp_w,
    const float* __restrict__ dt_w, const float* __restrict__ out_w,
    __hip_bfloat16* __restrict__ in_bf, __hip_bfloat16* __restrict__ xp_bf,
    __hip_bfloat16* __restrict__ dt_bf, __hip_bfloat16* __restrict__ out_bf) {
    int gi = blockIdx.x * 256 + threadIdx.x;
    if (gi >= NLAYER * N_CVT4) return;
    int layer = gi / N_CVT4;
    int i = gi - layer * N_CVT4;
    const float* src;
    __hip_bfloat16* dst;
    int off;
    if (i < N_IN4) {
        src = in_w + (size_t)layer * 4096 * 1024;
        dst = in_bf + (size_t)layer * 4096 * 1024; off = i;
    } else if (i < N_IN4 + N_XP4) {
        src = xp_w + (size_t)layer * 96 * 2048;
        dst = xp_bf + (size_t)layer * 128 * 2048; off = i - N_IN4;  // dst rows 96..127 stay poison (finite)
    } else if (i < N_IN4 + N_XP4 + N_DT4) {
        src = dt_w + (size_t)layer * 2048 * 64;
        dst = dt_bf + (size_t)layer * 2048 * 64; off = i - N_IN4 - N_XP4;
    } else {
        src = out_w + (size_t)layer * 1024 * 2048;
        dst = out_bf + (size_t)layer * 1024 * 2048; off = i - N_IN4 - N_XP4 - N_DT4;
    }
    float4 v = ((const float4*)src)[off];
    ushort4 o;
    o.x = f2bf(v.x); o.y = f2bf(v.y); o.z = f2bf(v.z); o.w = f2bf(v.w);
    ((ushort4*)dst)[off] = o;
}

// ---------------- RMSNorm -> bf16 ----------------
__global__ __launch_bounds__(256) void rmsnorm_kernel(const float* __restrict__ x,
                                                      const float* __restrict__ w,
                                                      __hip_bfloat16* __restrict__ out) {
    int row = blockIdx.x;
    const float* xr = x + (size_t)row * D;
    float v[4];
    float s = 0.f;
#pragma unroll
    for (int i = 0; i < 4; ++i) {
        v[i] = xr[threadIdx.x + i * 256];
        s += v[i] * v[i];
    }
#pragma unroll
    for (int off = 32; off > 0; off >>= 1) s += __shfl_xor(s, off, 64);
    __shared__ float red[4];
    int wave = threadIdx.x >> 6;
    if ((threadIdx.x & 63) == 0) red[wave] = s;
    __syncthreads();
    float tot = red[0] + red[1] + red[2] + red[3];
    float inv = rsqrtf(tot * (1.f / D) + 1e-5f);
#pragma unroll
    for (int i = 0; i < 4; ++i) {
        int c = threadIdx.x + i * 256;
        out[(size_t)row * D + c] = __float2bfloat16(v[i] * inv * w[c]);
    }
}

// ---------------- MFMA GEMM (m97 structure): C[M,N] = A[M,K]*B[N,K]^T ----------------
// Tile 128(M) x TN(N) x 32(K), 4 waves in 2x2; wave tile 64 x TN/2.
// EPI 0: plain; 1: softplus(c+bias[n]); 2: c+resid[m*ldc+n]
#define BK 32

template <int TN, int EPI>
__global__ __launch_bounds__(256, 2) void gemm_mfma(
    const __hip_bfloat16* __restrict__ A, int lda,
    const __hip_bfloat16* __restrict__ B, int ldb,
    float* __restrict__ C, int ldc, int Nvalid,
    int kchunk, long zstride,
    const float* __restrict__ bias, const float* __restrict__ resid) {
    constexpr int NF = TN / 32;          // N frags per wave
    constexpr int WCOLS = TN / 2;        // cols per wave column
    __shared__ __align__(16) __hip_bfloat16 As[128 * BK];
    __shared__ __align__(16) __hip_bfloat16 Bs[TN * BK];
    int tid = threadIdx.x;
    int wave = tid >> 6, lane = tid & 63;
    int m0 = blockIdx.y * 128, n0 = blockIdx.x * TN;
    int k_lo = blockIdx.z * kchunk;
    int k_hi = k_lo + kchunk;
    C += (long)blockIdx.z * zstride;
    int wr = wave >> 1, wc = wave & 1;
    int srow = lane >> 2, scol = (lane & 3) * 8;
    int q = lane >> 4, r = lane & 15;

    floatx4 acc[4][NF] = {};

    const __hip_bfloat16* gA0 = A + (long)(m0 + wave * 32 + srow) * lda + scol;
    const __hip_bfloat16* gA1 = gA0 + (long)16 * lda;
    __hip_bfloat16* lA0 = As + (wave * 32) * BK;
    __hip_bfloat16* lA1 = As + (wave * 32 + 16) * BK;
    const __hip_bfloat16* gB0;
    const __hip_bfloat16* gB1 = nullptr;
    __hip_bfloat16* lB0;
    __hip_bfloat16* lB1 = nullptr;
    if (TN == 128) {
        gB0 = B + (long)(n0 + wave * 32 + srow) * ldb + scol;
        gB1 = gB0 + (long)16 * ldb;
        lB0 = Bs + (wave * 32) * BK;
        lB1 = Bs + (wave * 32 + 16) * BK;
    } else {  // TN == 64
        gB0 = B + (long)(n0 + wave * 16 + srow) * ldb + scol;
        lB0 = Bs + (wave * 16) * BK;
    }

    for (int k0 = k_lo; k0 < k_hi; k0 += BK) {
#ifdef HAVE_GLD
        GLD(gA0 + k0, lA0);
        GLD(gA1 + k0, lA1);
        GLD(gB0 + k0, lB0);
        if (TN == 128) GLD(gB1 + k0, lB1);
#else
        *(short8*)(lA0 + lane * 8) = *(const short8*)(gA0 + k0 - scol + (lane & 3) * 8);
        *(short8*)(lA1 + lane * 8) = *(const short8*)(gA1 + k0 - scol + (lane & 3) * 8);
        *(short8*)(lB0 + lane * 8) = *(const short8*)(gB0 + k0 - scol + (lane & 3) * 8);
        if (TN == 128) *(short8*)(lB1 + lane * 8) = *(const short8*)(gB1 + k0 - scol + (lane & 3) * 8);
#endif
        __syncthreads();
        const short* Ap = (const short*)As;
        const short* Bp = (const short*)Bs;
        short8 af[4], bfr[NF];
#pragma unroll
        for (int i = 0; i < 4; ++i)
            af[i] = *(const short8*)(Ap + (wr * 64 + i * 16 + r) * BK + q * 8);
#pragma unroll
        for (int j = 0; j < NF; ++j)
            bfr[j] = *(const short8*)(Bp + (wc * WCOLS + j * 16 + r) * BK + q * 8);
#pragma unroll
        for (int i = 0; i < 4; ++i)
#pragma unroll
            for (int j = 0; j < NF; ++j)
                acc[i][j] = __builtin_amdgcn_mfma_f32_16x16x32_bf16(af[i], bfr[j], acc[i][j], 0, 0, 0);
        __syncthreads();
    }

#pragma unroll
    for (int i = 0; i < 4; ++i) {
        int mrow = m0 + wr * 64 + i * 16 + q * 4;
#pragma unroll
        for (int j = 0; j < NF; ++j) {
            int ncol = n0 + wc * WCOLS + j * 16 + r;
            if (ncol < Nvalid) {
#pragma unroll
                for (int rr = 0; rr < 4; ++rr) {
                    float v = acc[i][j][rr];
                    int m = mrow + rr;
                    if (EPI == 1) {
                        v += bias[ncol];
                        v = v > 20.f ? v : log1pf(__expf(v));
                    } else if (EPI == 2) {
                        v += resid[(long)m * ldc + ncol];
                    }
                    C[(long)m * ldc + ncol] = v;
                }
            }
        }
    }
}

// ---------------- causal depthwise conv + bias + SiLU -> bf16 ----------------
__global__ __launch_bounds__(256) void conv_silu_kernel(const float* __restrict__ xz,
                                                        const float* __restrict__ cw,
                                                        const float* __restrict__ cb,
                                                        __hip_bfloat16* __restrict__ u) {
    int idx = blockIdx.x * 256 + threadIdx.x;  // t*DI + d
    int d = idx & (DI - 1);
    int t = idx >> 11;
    float acc = cb[d];
#pragma unroll
    for (int k = 0; k < KCONV; ++k) {
        int tk = t - (KCONV - 1) + k;
        if (tk >= 0) acc += xz[(size_t)tk * (2 * DI) + d] * cw[d * KCONV + k];
    }
    u[idx] = __float2bfloat16(siluf(acc));
}

// ---------------- x_proj split-K reduce ----------------
__global__ __launch_bounds__(256) void xdbl_reduce_kernel(const float* __restrict__ part,
                                                          float* __restrict__ xdbl,
                                                          __hip_bfloat16* __restrict__ xdbl_bf) {
    int i = blockIdx.x * 256 + threadIdx.x;  // < L*XD
    float s = 0.f;
#pragma unroll
    for (int sp = 0; sp < KSPLIT; ++sp) s += part[(long)sp * L * XD + i];
    xdbl[i] = s;
    xdbl_bf[i] = __float2bfloat16(s);
}

// ---------------- selective scan: phase A (per-chunk aggregates) ----------------
__global__ __launch_bounds__(256) void scanA_kernel(const float* __restrict__ delta,
                                                    const __hip_bfloat16* __restrict__ u,
                                                    const float* __restrict__ xdbl,
                                                    const float* __restrict__ Alog,
                                                    float* __restrict__ Ach,
                                                    float* __restrict__ Bch) {
    int d = blockIdx.x * 256 + threadIdx.x;
    int c = blockIdx.y;
    __shared__ __align__(16) float Bsh[CT * NSTATE];
    int tt0 = threadIdx.x >> 4, c0 = threadIdx.x & 15;
    Bsh[threadIdx.x] = xdbl[(size_t)(c * CT + tt0) * XD + DTR + c0];
    __syncthreads();

    float aval[NSTATE];
    const float4* Al4 = (const float4*)(Alog + (size_t)d * NSTATE);
#pragma unroll
    for (int n4 = 0; n4 < 4; ++n4) {
        float4 t = Al4[n4];
        aval[n4 * 4 + 0] = -__expf(t.x);
        aval[n4 * 4 + 1] = -__expf(t.y);
        aval[n4 * 4 + 2] = -__expf(t.z);
        aval[n4 * 4 + 3] = -__expf(t.w);
    }
    float h[NSTATE], ap[NSTATE];
#pragma unroll
    for (int n = 0; n < NSTATE; ++n) { h[n] = 0.f; ap[n] = 1.f; }

    for (int tt = 0; tt < CT; ++tt) {
        int t = c * CT + tt;
        float dl = delta[(size_t)t * DI + d];
        float uu = __bfloat162float(u[(size_t)t * DI + d]);
        float du = dl * uu;
        const float4* Bv = (const float4*)(Bsh + tt * NSTATE);
#pragma unroll
        for (int n4 = 0; n4 < 4; ++n4) {
            float4 b = Bv[n4];
            float bb[4] = {b.x, b.y, b.z, b.w};
#pragma unroll
            for (int k = 0; k < 4; ++k) {
                int n = n4 * 4 + k;
                float a = __expf(dl * aval[n]);
                h[n] = a * h[n] + du * bb[k];
                ap[n] *= a;
            }
        }
    }
    float4* Ao = (float4*)(Ach + ((size_t)c * DI + d) * NSTATE);
    float4* Bo = (float4*)(Bch + ((size_t)c * DI + d) * NSTATE);
#pragma unroll
    for (int n4 = 0; n4 < 4; ++n4) {
        Ao[n4] = make_float4(ap[n4 * 4], ap[n4 * 4 + 1], ap[n4 * 4 + 2], ap[n4 * 4 + 3]);
        Bo[n4] = make_float4(h[n4 * 4], h[n4 * 4 + 1], h[n4 * 4 + 2], h[n4 * 4 + 3]);
    }
}

// ---------------- scan phase B: sequential chunk combine; Hinit overwrites Ach ----------------
__global__ __launch_bounds__(256) void scanB_kernel(float* __restrict__ Ach,
                                                    const float* __restrict__ Bch) {
    long i = blockIdx.x * 256 + threadIdx.x;  // < DI*NSTATE
    const long S = (long)DI * NSTATE;
    float h = 0.f;
    for (int c = 0; c < NC; ++c) {
        float a = Ach[c * S + i];
        float b = Bch[c * S + i];
        Ach[c * S + i] = h;  // becomes Hinit
        h = a * h + b;
    }
}

// ---------------- scan phase C: replay with init state, fused gate -> yg bf16 ----------------
__global__ __launch_bounds__(256) void scanC_kernel(const float* __restrict__ delta,
                                                    const __hip_bfloat16* __restrict__ u,
                                                    const float* __restrict__ xdbl,
                                                    const float* __restrict__ Alog,
                                                    const float* __restrict__ Hin,
                                                    const float* __restrict__ xz,
                                                    const float* __restrict__ Dskip,
                                                    __hip_bfloat16* __restrict__ yg) {
    int d = blockIdx.x * 256 + threadIdx.x;
    int c = blockIdx.y;
    __shared__ __align__(16) float Bsh[CT * NSTATE];
    __shared__ __align__(16) float Csh[CT * NSTATE];
    int tt0 = threadIdx.x >> 4, c0 = threadIdx.x & 15;
    Bsh[threadIdx.x] = xdbl[(size_t)(c * CT + tt0) * XD + DTR + c0];
    Csh[threadIdx.x] = xdbl[(size_t)(c * CT + tt0) * XD + DTR + NSTATE + c0];
    __syncthreads();

    float aval[NSTATE];
    const float4* Al4 = (const float4*)(Alog + (size_t)d * NSTATE);
#pragma unroll
    for (int n4 = 0; n4 < 4; ++n4) {
        float4 t = Al4[n4];
        aval[n4 * 4 + 0] = -__expf(t.x);
        aval[n4 * 4 + 1] = -__expf(t.y);
        aval[n4 * 4 + 2] = -__expf(t.z);
        aval[n4 * 4 + 3] = -__expf(t.w);
    }
    float h[NSTATE];
    const float4* Hi = (const float4*)(Hin + ((size_t)c * DI + d) * NSTATE);
#pragma unroll
    for (int n4 = 0; n4 < 4; ++n4) {
        float4 t = Hi[n4];
        h[n4 * 4 + 0] = t.x; h[n4 * 4 + 1] = t.y; h[n4 * 4 + 2] = t.z; h[n4 * 4 + 3] = t.w;
    }
    float dsk = Dskip[d];

    for (int tt = 0; tt < CT; ++tt) {
        int t = c * CT + tt;
        float dl = delta[(size_t)t * DI + d];
        float uu = __bfloat162float(u[(size_t)t * DI + d]);
        float du = dl * uu;
        const float4* Bv = (const float4*)(Bsh + tt * NSTATE);
        const float4* Cv = (const float4*)(Csh + tt * NSTATE);
        float y = 0.f;
#pragma unroll
        for (int n4 = 0; n4 < 4; ++n4) {
            float4 b = Bv[n4];
            float4 cc = Cv[n4];
            float bb[4] = {b.x, b.y, b.z, b.w};
            float cv[4] = {cc.x, cc.y, cc.z, cc.w};
#pragma unroll
            for (int k = 0; k < 4; ++k) {
                int n = n4 * 4 + k;
                float a = __expf(dl * aval[n]);
                h[n] = a * h[n] + du * bb[k];
                y += h[n] * cv[k];
            }
        }
        float z = xz[(size_t)t * (2 * DI) + DI + d];
        yg[(size_t)t * DI + d] = __float2bfloat16((y + uu * dsk) * siluf(z));
    }
}

// ---------------- host orchestration ----------------
extern "C" void kernel_launch(void* const* d_in, const int* in_sizes, int n_in,
                              void* d_out, int out_size, void* d_ws, size_t ws_size,
                              hipStream_t stream) {
    const float* x      = (const float*)d_in[0];
    const float* norm_w = (const float*)d_in[1];
    const float* in_w   = (const float*)d_in[2];
    const float* conv_w = (const float*)d_in[3];
    const float* conv_b = (const float*)d_in[4];
    const float* xproj_w= (const float*)d_in[5];
    const float* dt_w   = (const float*)d_in[6];
    const float* dt_b   = (const float*)d_in[7];
    const float* A_log  = (const float*)d_in[8];
    const float* D_skip = (const float*)d_in[9];
    const float* out_w  = (const float*)d_in[10];
    float* out = (float*)d_out;

    uint8_t* wp = (uint8_t*)d_ws;
    auto alloc = [&](size_t bytes) {
        uint8_t* p = wp;
        wp += (bytes + 255) & ~(size_t)255;
        return p;
    };
    __hip_bfloat16* w_in_bf  = (__hip_bfloat16*)alloc((size_t)NLAYER * 4096 * 1024 * 2);
    __hip_bfloat16* w_xp_bf  = (__hip_bfloat16*)alloc((size_t)NLAYER * 128 * 2048 * 2);
    __hip_bfloat16* w_dt_bf  = (__hip_bfloat16*)alloc((size_t)NLAYER * 2048 * 64 * 2);
    __hip_bfloat16* w_out_bf = (__hip_bfloat16*)alloc((size_t)NLAYER * 1024 * 2048 * 2);
    __hip_bfloat16* xn_bf    = (__hip_bfloat16*)alloc((size_t)L * D * 2);
    float*          xz       = (float*)alloc((size_t)L * 2 * DI * 4);
    __hip_bfloat16* u_bf     = (__hip_bfloat16*)alloc((size_t)L * DI * 2);
    float*          xdbl     = (float*)alloc((size_t)L * XD * 4);
    __hip_bfloat16* xdbl_bf  = (__hip_bfloat16*)alloc((size_t)L * XD * 2);
    float*          part     = (float*)alloc((size_t)KSPLIT * L * XD * 4);
    float*          delta    = (float*)alloc((size_t)L * DI * 4);
    __hip_bfloat16* yg_bf    = (__hip_bfloat16*)alloc((size_t)L * DI * 2);
    float*          Ach      = (float*)alloc((size_t)NC * DI * NSTATE * 4);  // Hinit aliases this
    float*          Bch      = (float*)alloc((size_t)NC * DI * NSTATE * 4);

    cvt_all_kernel<<<(NLAYER * N_CVT4 + 255) / 256, 256, 0, stream>>>(
        in_w, xproj_w, dt_w, out_w, w_in_bf, w_xp_bf, w_dt_bf, w_out_bf);

    for (int l = 0; l < NLAYER; ++l) {
        const float* xin = (l == 0) ? x : out;
        const __hip_bfloat16* wi = w_in_bf + (size_t)l * 4096 * 1024;
        const __hip_bfloat16* wx = w_xp_bf + (size_t)l * 128 * 2048;
        const __hip_bfloat16* wd = w_dt_bf + (size_t)l * 2048 * 64;
        const __hip_bfloat16* wo = w_out_bf + (size_t)l * 1024 * 2048;

        rmsnorm_kernel<<<L, 256, 0, stream>>>(xin, norm_w + (size_t)l * D, xn_bf);

        // in_proj: [1024,1024] x [4096,1024]^T -> xz [1024,4096]
        gemm_mfma<128, 0><<<dim3(4096 / 128, L / 128, 1), 256, 0, stream>>>(
            xn_bf, D, wi, D, xz, 4096, 4096, D, 0, nullptr, nullptr);

        conv_silu_kernel<<<L * DI / 256, 256, 0, stream>>>(
            xz, conv_w + (size_t)l * DI * KCONV, conv_b + (size_t)l * DI, u_bf);

        // x_proj split-K: [1024,2048] x [96(pad128),2048]^T -> part[s][1024][96]
        gemm_mfma<128, 0><<<dim3(1, L / 128, KSPLIT), 256, 0, stream>>>(
            u_bf, DI, wx, DI, part, XD, XD, DI / KSPLIT, (long)L * XD, nullptr, nullptr);
        xdbl_reduce_kernel<<<(L * XD) / 256, 256, 0, stream>>>(part, xdbl, xdbl_bf);

        // dt_proj: [1024,96(use 64)] x [2048,64]^T -> delta with softplus(+bias)
        gemm_mfma<128, 1><<<dim3(2048 / 128, L / 128, 1), 256, 0, stream>>>(
            xdbl_bf, XD, wd, DTR, delta, DI, DI, DTR, 0,
            dt_b + (size_t)l * DI, nullptr);

        scanA_kernel<<<dim3(DI / 256, NC), 256, 0, stream>>>(
            delta, u_bf, xdbl, A_log + (size_t)l * DI * NSTATE, Ach, Bch);
        scanB_kernel<<<(DI * NSTATE) / 256, 256, 0, stream>>>(Ach, Bch);
        scanC_kernel<<<dim3(DI / 256, NC), 256, 0, stream>>>(
            delta, u_bf, xdbl, A_log + (size_t)l * DI * NSTATE, Ach, xz,
            D_skip + (size_t)l * DI, yg_bf);

        // out_proj: [1024,2048] x [1024,2048]^T + resid -> out (TN=64 keeps 128 blocks)
        gemm_mfma<64, 2><<<dim3(1024 / 64, L / 128, 1), 256, 0, stream>>>(
            yg_bf, DI, wo, DI, out, D, D, DI, 0, nullptr, xin);
    }
}

// Round 4
// 669.279 us; speedup vs baseline: 1.0895x; 1.0895x over previous
//
#include <hip/hip_runtime.h>
#include <hip/hip_bf16.h>
#include <stdint.h>

#define L 1024
#define D 1024
#define NLAYER 4
#define NSTATE 16
#define DI 2048
#define DTR 64
#define KCONV 4
#define XD 96      // DTR + 2*NSTATE
#define NC 64      // scan chunks
#define CT 16      // timesteps per chunk (L/NC)
#define KSPLIT 8   // x_proj split-K

typedef __attribute__((ext_vector_type(8))) short short8;
typedef __attribute__((ext_vector_type(4))) float floatx4;

__device__ __forceinline__ float siluf(float x) { return x / (1.f + __expf(-x)); }

__device__ __forceinline__ unsigned int f2bf2(float lo, float hi) {
    __hip_bfloat16 a = __float2bfloat16(lo), b = __float2bfloat16(hi);
    return (unsigned int)*reinterpret_cast<unsigned short*>(&a) |
           ((unsigned int)*reinterpret_cast<unsigned short*>(&b) << 16);
}

#ifndef __has_builtin
#define __has_builtin(x) 0
#endif
#if __has_builtin(__builtin_amdgcn_global_load_lds)
#define HAVE_GLD 1
#define GLD(gp, lp) __builtin_amdgcn_global_load_lds(                                  \
    (const __attribute__((address_space(1))) void*)(gp),                               \
    (__attribute__((address_space(3))) void*)(lp), 16, 0, 0)
#endif

// ---------------- all-layer weight fp32->bf16 conversion (1 launch, 64B/thread) ----------------
#define N_IN4  1048576   // 4096*1024/4
#define N_XP4  49152     // 96*2048/4
#define N_DT4  32768     // 2048*64/4
#define N_OUT4 524288    // 1024*2048/4
#define N_CVT4 (N_IN4 + N_XP4 + N_DT4 + N_OUT4)
#define CVT_THREADS (NLAYER * N_CVT4 / 4)

__global__ __launch_bounds__(256) void cvt_all_kernel(
    const float* __restrict__ in_w, const float* __restrict__ xp_w,
    const float* __restrict__ dt_w, const float* __restrict__ out_w,
    __hip_bfloat16* __restrict__ in_bf, __hip_bfloat16* __restrict__ xp_bf,
    __hip_bfloat16* __restrict__ dt_bf, __hip_bfloat16* __restrict__ out_bf) {
    int gi = blockIdx.x * 256 + threadIdx.x;
    if (gi >= CVT_THREADS) return;
    int layer = gi / (N_CVT4 / 4);
    int i = (gi - layer * (N_CVT4 / 4)) * 4;   // float4 index within layer, multiple of 4
    const float* src;
    __hip_bfloat16* dst;
    int off;
    if (i < N_IN4) {
        src = in_w + (size_t)layer * 4096 * 1024;
        dst = in_bf + (size_t)layer * 4096 * 1024; off = i;
    } else if (i < N_IN4 + N_XP4) {
        src = xp_w + (size_t)layer * 96 * 2048;
        dst = xp_bf + (size_t)layer * 128 * 2048; off = i - N_IN4;  // rows 96..127 stay poison (finite)
    } else if (i < N_IN4 + N_XP4 + N_DT4) {
        src = dt_w + (size_t)layer * 2048 * 64;
        dst = dt_bf + (size_t)layer * 2048 * 64; off = i - N_IN4 - N_XP4;
    } else {
        src = out_w + (size_t)layer * 1024 * 2048;
        dst = out_bf + (size_t)layer * 1024 * 2048; off = i - N_IN4 - N_XP4 - N_DT4;
    }
    const float4* s4 = (const float4*)src + off;
    unsigned int o[8];
#pragma unroll
    for (int j = 0; j < 4; ++j) {
        float4 v = s4[j];
        o[j * 2 + 0] = f2bf2(v.x, v.y);
        o[j * 2 + 1] = f2bf2(v.z, v.w);
    }
    uint4* dp = (uint4*)((unsigned short*)dst + (size_t)off * 4);
    dp[0] = make_uint4(o[0], o[1], o[2], o[3]);
    dp[1] = make_uint4(o[4], o[5], o[6], o[7]);
}

// ---------------- RMSNorm -> bf16 ----------------
__global__ __launch_bounds__(256) void rmsnorm_kernel(const float* __restrict__ x,
                                                      const float* __restrict__ w,
                                                      __hip_bfloat16* __restrict__ out) {
    int row = blockIdx.x;
    const float* xr = x + (size_t)row * D;
    float v[4];
    float s = 0.f;
#pragma unroll
    for (int i = 0; i < 4; ++i) {
        v[i] = xr[threadIdx.x + i * 256];
        s += v[i] * v[i];
    }
#pragma unroll
    for (int off = 32; off > 0; off >>= 1) s += __shfl_xor(s, off, 64);
    __shared__ float red[4];
    int wave = threadIdx.x >> 6;
    if ((threadIdx.x & 63) == 0) red[wave] = s;
    __syncthreads();
    float tot = red[0] + red[1] + red[2] + red[3];
    float inv = rsqrtf(tot * (1.f / D) + 1e-5f);
#pragma unroll
    for (int i = 0; i < 4; ++i) {
        int c = threadIdx.x + i * 256;
        out[(size_t)row * D + c] = __float2bfloat16(v[i] * inv * w[c]);
    }
}

// ---------------- MFMA GEMM, double-buffered single-barrier K-loop ----------------
// C[M,N] = A[M,K]*B[N,K]^T. Tile 128(M) x TN(N) x 32(K), 4 waves 2x2.
// Pipeline: stage(k0) -> loop { barrier (drains prev stage); stage(k0+BK); frags+MFMA }
// The prefetch issued after the barrier has the whole MFMA span to land.
// EPI 0: plain; 1: softplus(c+bias[n]); 2: c+resid[m*ldc+n]
#define BK 32

template <int TN, int EPI>
__global__ __launch_bounds__(256, 2) void gemm_mfma(
    const __hip_bfloat16* __restrict__ A, int lda,
    const __hip_bfloat16* __restrict__ B, int ldb,
    float* __restrict__ C, int ldc, int Nvalid,
    int kchunk, long zstride,
    const float* __restrict__ bias, const float* __restrict__ resid) {
    constexpr int NF = TN / 32;          // N frags per wave
    constexpr int WCOLS = TN / 2;        // cols per wave column
    __shared__ __align__(16) __hip_bfloat16 As[2][128 * BK];
    __shared__ __align__(16) __hip_bfloat16 Bs[2][TN * BK];
    int tid = threadIdx.x;
    int wave = tid >> 6, lane = tid & 63;
    int m0 = blockIdx.y * 128, n0 = blockIdx.x * TN;
    int k_lo = blockIdx.z * kchunk;
    int k_hi = k_lo + kchunk;
    C += (long)blockIdx.z * zstride;
    int wr = wave >> 1, wc = wave & 1;
    int srow = lane >> 2, scol = (lane & 3) * 8;
    int q = lane >> 4, r = lane & 15;

    floatx4 acc[4][NF] = {};

    const __hip_bfloat16* gA0 = A + (long)(m0 + wave * 32 + srow) * lda + scol;
    const __hip_bfloat16* gA1 = gA0 + (long)16 * lda;
    const __hip_bfloat16* gB0;
    const __hip_bfloat16* gB1 = nullptr;
    if (TN == 128) {
        gB0 = B + (long)(n0 + wave * 32 + srow) * ldb + scol;
        gB1 = gB0 + (long)16 * ldb;
    } else {
        gB0 = B + (long)(n0 + wave * 16 + srow) * ldb + scol;
    }

    auto stage = [&](int k0, int p) {
#ifdef HAVE_GLD
        GLD(gA0 + k0, &As[p][(wave * 32) * BK]);
        GLD(gA1 + k0, &As[p][(wave * 32 + 16) * BK]);
        GLD(gB0 + k0, &Bs[p][(wave * (TN == 128 ? 32 : 16)) * BK]);
        if (TN == 128) GLD(gB1 + k0, &Bs[p][(wave * 32 + 16) * BK]);
#else
        *(short8*)(&As[p][(wave * 32) * BK] + lane * 8) = *(const short8*)(gA0 + k0);
        *(short8*)(&As[p][(wave * 32 + 16) * BK] + lane * 8) = *(const short8*)(gA1 + k0);
        *(short8*)(&Bs[p][(wave * (TN == 128 ? 32 : 16)) * BK] + lane * 8) = *(const short8*)(gB0 + k0);
        if (TN == 128) *(short8*)(&Bs[p][(wave * 32 + 16) * BK] + lane * 8) = *(const short8*)(gB1 + k0);
#endif
    };

    stage(k_lo, 0);
    int p = 0;
    for (int k0 = k_lo; k0 < k_hi; k0 += BK) {
        __syncthreads();                       // drains the stage issued last iter (or prologue)
        if (k0 + BK < k_hi) stage(k0 + BK, p ^ 1);
        const short* Ap = (const short*)As[p];
        const short* Bp = (const short*)Bs[p];
        short8 af[4], bfr[NF];
#pragma unroll
        for (int i = 0; i < 4; ++i)
            af[i] = *(const short8*)(Ap + (wr * 64 + i * 16 + r) * BK + q * 8);
#pragma unroll
        for (int j = 0; j < NF; ++j)
            bfr[j] = *(const short8*)(Bp + (wc * WCOLS + j * 16 + r) * BK + q * 8);
#pragma unroll
        for (int i = 0; i < 4; ++i)
#pragma unroll
            for (int j = 0; j < NF; ++j)
                acc[i][j] = __builtin_amdgcn_mfma_f32_16x16x32_bf16(af[i], bfr[j], acc[i][j], 0, 0, 0);
        p ^= 1;
    }

#pragma unroll
    for (int i = 0; i < 4; ++i) {
        int mrow = m0 + wr * 64 + i * 16 + q * 4;
#pragma unroll
        for (int j = 0; j < NF; ++j) {
            int ncol = n0 + wc * WCOLS + j * 16 + r;
            if (ncol < Nvalid) {
#pragma unroll
                for (int rr = 0; rr < 4; ++rr) {
                    float v = acc[i][j][rr];
                    int m = mrow + rr;
                    if (EPI == 1) {
                        v += bias[ncol];
                        v = v > 20.f ? v : log1pf(__expf(v));
                    } else if (EPI == 2) {
                        v += resid[(long)m * ldc + ncol];
                    }
                    C[(long)m * ldc + ncol] = v;
                }
            }
        }
    }
}

// ---------------- causal depthwise conv + bias + SiLU -> bf16 ----------------
__global__ __launch_bounds__(256) void conv_silu_kernel(const float* __restrict__ xz,
                                                        const float* __restrict__ cw,
                                                        const float* __restrict__ cb,
                                                        __hip_bfloat16* __restrict__ u) {
    int idx = blockIdx.x * 256 + threadIdx.x;  // t*DI + d
    int d = idx & (DI - 1);
    int t = idx >> 11;
    float acc = cb[d];
#pragma unroll
    for (int k = 0; k < KCONV; ++k) {
        int tk = t - (KCONV - 1) + k;
        if (tk >= 0) acc += xz[(size_t)tk * (2 * DI) + d] * cw[d * KCONV + k];
    }
    u[idx] = __float2bfloat16(siluf(acc));
}

// ---------------- x_proj split-K reduce ----------------
__global__ __launch_bounds__(256) void xdbl_reduce_kernel(const float* __restrict__ part,
                                                          float* __restrict__ xdbl,
                                                          __hip_bfloat16* __restrict__ xdbl_bf) {
    int i = blockIdx.x * 256 + threadIdx.x;  // < L*XD
    float s = 0.f;
#pragma unroll
    for (int sp = 0; sp < KSPLIT; ++sp) s += part[(long)sp * L * XD + i];
    xdbl[i] = s;
    xdbl_bf[i] = __float2bfloat16(s);
}

// ---------------- selective scan: phase A (per-chunk aggregates) ----------------
__global__ __launch_bounds__(256) void scanA_kernel(const float* __restrict__ delta,
                                                    const __hip_bfloat16* __restrict__ u,
                                                    const float* __restrict__ xdbl,
                                                    const float* __restrict__ Alog,
                                                    float* __restrict__ Ach,
                                                    float* __restrict__ Bch) {
    int d = blockIdx.x * 256 + threadIdx.x;
    int c = blockIdx.y;
    __shared__ __align__(16) float Bsh[CT * NSTATE];
    int tt0 = threadIdx.x >> 4, c0 = threadIdx.x & 15;
    Bsh[threadIdx.x] = xdbl[(size_t)(c * CT + tt0) * XD + DTR + c0];
    __syncthreads();

    float aval[NSTATE];
    const float4* Al4 = (const float4*)(Alog + (size_t)d * NSTATE);
#pragma unroll
    for (int n4 = 0; n4 < 4; ++n4) {
        float4 t = Al4[n4];
        aval[n4 * 4 + 0] = -__expf(t.x);
        aval[n4 * 4 + 1] = -__expf(t.y);
        aval[n4 * 4 + 2] = -__expf(t.z);
        aval[n4 * 4 + 3] = -__expf(t.w);
    }
    float h[NSTATE], ap[NSTATE];
#pragma unroll
    for (int n = 0; n < NSTATE; ++n) { h[n] = 0.f; ap[n] = 1.f; }

    for (int tt = 0; tt < CT; ++tt) {
        int t = c * CT + tt;
        float dl = delta[(size_t)t * DI + d];
        float uu = __bfloat162float(u[(size_t)t * DI + d]);
        float du = dl * uu;
        const float4* Bv = (const float4*)(Bsh + tt * NSTATE);
#pragma unroll
        for (int n4 = 0; n4 < 4; ++n4) {
            float4 b = Bv[n4];
            float bb[4] = {b.x, b.y, b.z, b.w};
#pragma unroll
            for (int k = 0; k < 4; ++k) {
                int n = n4 * 4 + k;
                float a = __expf(dl * aval[n]);
                h[n] = a * h[n] + du * bb[k];
                ap[n] *= a;
            }
        }
    }
    float4* Ao = (float4*)(Ach + ((size_t)c * DI + d) * NSTATE);
    float4* Bo = (float4*)(Bch + ((size_t)c * DI + d) * NSTATE);
#pragma unroll
    for (int n4 = 0; n4 < 4; ++n4) {
        Ao[n4] = make_float4(ap[n4 * 4], ap[n4 * 4 + 1], ap[n4 * 4 + 2], ap[n4 * 4 + 3]);
        Bo[n4] = make_float4(h[n4 * 4], h[n4 * 4 + 1], h[n4 * 4 + 2], h[n4 * 4 + 3]);
    }
}

// ---------------- scan phase B: sequential chunk combine; Hinit overwrites Ach ----------------
__global__ __launch_bounds__(256) void scanB_kernel(float* __restrict__ Ach,
                                                    const float* __restrict__ Bch) {
    long i = blockIdx.x * 256 + threadIdx.x;  // < DI*NSTATE
    const long S = (long)DI * NSTATE;
    float h = 0.f;
    for (int c = 0; c < NC; ++c) {
        float a = Ach[c * S + i];
        float b = Bch[c * S + i];
        Ach[c * S + i] = h;  // becomes Hinit
        h = a * h + b;
    }
}

// ---------------- scan phase C: replay with init state, fused gate -> yg bf16 ----------------
__global__ __launch_bounds__(256) void scanC_kernel(const float* __restrict__ delta,
                                                    const __hip_bfloat16* __restrict__ u,
                                                    const float* __restrict__ xdbl,
                                                    const float* __restrict__ Alog,
                                                    const float* __restrict__ Hin,
                                                    const float* __restrict__ xz,
                                                    const float* __restrict__ Dskip,
                                                    __hip_bfloat16* __restrict__ yg) {
    int d = blockIdx.x * 256 + threadIdx.x;
    int c = blockIdx.y;
    __shared__ __align__(16) float Bsh[CT * NSTATE];
    __shared__ __align__(16) float Csh[CT * NSTATE];
    int tt0 = threadIdx.x >> 4, c0 = threadIdx.x & 15;
    Bsh[threadIdx.x] = xdbl[(size_t)(c * CT + tt0) * XD + DTR + c0];
    Csh[threadIdx.x] = xdbl[(size_t)(c * CT + tt0) * XD + DTR + NSTATE + c0];
    __syncthreads();

    float aval[NSTATE];
    const float4* Al4 = (const float4*)(Alog + (size_t)d * NSTATE);
#pragma unroll
    for (int n4 = 0; n4 < 4; ++n4) {
        float4 t = Al4[n4];
        aval[n4 * 4 + 0] = -__expf(t.x);
        aval[n4 * 4 + 1] = -__expf(t.y);
        aval[n4 * 4 + 2] = -__expf(t.z);
        aval[n4 * 4 + 3] = -__expf(t.w);
    }
    float h[NSTATE];
    const float4* Hi = (const float4*)(Hin + ((size_t)c * DI + d) * NSTATE);
#pragma unroll
    for (int n4 = 0; n4 < 4; ++n4) {
        float4 t = Hi[n4];
        h[n4 * 4 + 0] = t.x; h[n4 * 4 + 1] = t.y; h[n4 * 4 + 2] = t.z; h[n4 * 4 + 3] = t.w;
    }
    float dsk = Dskip[d];

    for (int tt = 0; tt < CT; ++tt) {
        int t = c * CT + tt;
        float dl = delta[(size_t)t * DI + d];
        float uu = __bfloat162float(u[(size_t)t * DI + d]);
        float du = dl * uu;
        const float4* Bv = (const float4*)(Bsh + tt * NSTATE);
        const float4* Cv = (const float4*)(Csh + tt * NSTATE);
        float y = 0.f;
#pragma unroll
        for (int n4 = 0; n4 < 4; ++n4) {
            float4 b = Bv[n4];
            float4 cc = Cv[n4];
            float bb[4] = {b.x, b.y, b.z, b.w};
            float cv[4] = {cc.x, cc.y, cc.z, cc.w};
#pragma unroll
            for (int k = 0; k < 4; ++k) {
                int n = n4 * 4 + k;
                float a = __expf(dl * aval[n]);
                h[n] = a * h[n] + du * bb[k];
                y += h[n] * cv[k];
            }
        }
        float z = xz[(size_t)t * (2 * DI) + DI + d];
        yg[(size_t)t * DI + d] = __float2bfloat16((y + uu * dsk) * siluf(z));
    }
}

// ---------------- host orchestration ----------------
extern "C" void kernel_launch(void* const* d_in, const int* in_sizes, int n_in,
                              void* d_out, int out_size, void* d_ws, size_t ws_size,
                              hipStream_t stream) {
    const float* x      = (const float*)d_in[0];
    const float* norm_w = (const float*)d_in[1];
    const float* in_w   = (const float*)d_in[2];
    const float* conv_w = (const float*)d_in[3];
    const float* conv_b = (const float*)d_in[4];
    const float* xproj_w= (const float*)d_in[5];
    const float* dt_w   = (const float*)d_in[6];
    const float* dt_b   = (const float*)d_in[7];
    const float* A_log  = (const float*)d_in[8];
    const float* D_skip = (const float*)d_in[9];
    const float* out_w  = (const float*)d_in[10];
    float* out = (float*)d_out;

    uint8_t* wp = (uint8_t*)d_ws;
    auto alloc = [&](size_t bytes) {
        uint8_t* p = wp;
        wp += (bytes + 255) & ~(size_t)255;
        return p;
    };
    __hip_bfloat16* w_in_bf  = (__hip_bfloat16*)alloc((size_t)NLAYER * 4096 * 1024 * 2);
    __hip_bfloat16* w_xp_bf  = (__hip_bfloat16*)alloc((size_t)NLAYER * 128 * 2048 * 2);
    __hip_bfloat16* w_dt_bf  = (__hip_bfloat16*)alloc((size_t)NLAYER * 2048 * 64 * 2);
    __hip_bfloat16* w_out_bf = (__hip_bfloat16*)alloc((size_t)NLAYER * 1024 * 2048 * 2);
    __hip_bfloat16* xn_bf    = (__hip_bfloat16*)alloc((size_t)L * D * 2);
    float*          xz       = (float*)alloc((size_t)L * 2 * DI * 4);
    __hip_bfloat16* u_bf     = (__hip_bfloat16*)alloc((size_t)L * DI * 2);
    float*          xdbl     = (float*)alloc((size_t)L * XD * 4);
    __hip_bfloat16* xdbl_bf  = (__hip_bfloat16*)alloc((size_t)L * XD * 2);
    float*          part     = (float*)alloc((size_t)KSPLIT * L * XD * 4);
    float*          delta    = (float*)alloc((size_t)L * DI * 4);
    __hip_bfloat16* yg_bf    = (__hip_bfloat16*)alloc((size_t)L * DI * 2);
    float*          Ach      = (float*)alloc((size_t)NC * DI * NSTATE * 4);  // Hinit aliases this
    float*          Bch      = (float*)alloc((size_t)NC * DI * NSTATE * 4);

    cvt_all_kernel<<<(CVT_THREADS + 255) / 256, 256, 0, stream>>>(
        in_w, xproj_w, dt_w, out_w, w_in_bf, w_xp_bf, w_dt_bf, w_out_bf);

    for (int l = 0; l < NLAYER; ++l) {
        const float* xin = (l == 0) ? x : out;
        const __hip_bfloat16* wi = w_in_bf + (size_t)l * 4096 * 1024;
        const __hip_bfloat16* wx = w_xp_bf + (size_t)l * 128 * 2048;
        const __hip_bfloat16* wd = w_dt_bf + (size_t)l * 2048 * 64;
        const __hip_bfloat16* wo = w_out_bf + (size_t)l * 1024 * 2048;

        rmsnorm_kernel<<<L, 256, 0, stream>>>(xin, norm_w + (size_t)l * D, xn_bf);

        // in_proj: [1024,1024] x [4096,1024]^T -> xz [1024,4096]
        gemm_mfma<64, 0><<<dim3(4096 / 64, L / 128, 1), 256, 0, stream>>>(
            xn_bf, D, wi, D, xz, 4096, 4096, D, 0, nullptr, nullptr);

        conv_silu_kernel<<<L * DI / 256, 256, 0, stream>>>(
            xz, conv_w + (size_t)l * DI * KCONV, conv_b + (size_t)l * DI, u_bf);

        // x_proj split-K: [1024,2048] x [96(pad128),2048]^T -> part[s][1024][96]
        gemm_mfma<64, 0><<<dim3(2, L / 128, KSPLIT), 256, 0, stream>>>(
            u_bf, DI, wx, DI, part, XD, XD, DI / KSPLIT, (long)L * XD, nullptr, nullptr);
        xdbl_reduce_kernel<<<(L * XD) / 256, 256, 0, stream>>>(part, xdbl, xdbl_bf);

        // dt_proj: [1024,96(use 64)] x [2048,64]^T -> delta with softplus(+bias)
        gemm_mfma<64, 1><<<dim3(2048 / 64, L / 128, 1), 256, 0, stream>>>(
            xdbl_bf, XD, wd, DTR, delta, DI, DI, DTR, 0,
            dt_b + (size_t)l * DI, nullptr);

        scanA_kernel<<<dim3(DI / 256, NC), 256, 0, stream>>>(
            delta, u_bf, xdbl, A_log + (size_t)l * DI * NSTATE, Ach, Bch);
        scanB_kernel<<<(DI * NSTATE) / 256, 256, 0, stream>>>(Ach, Bch);
        scanC_kernel<<<dim3(DI / 256, NC), 256, 0, stream>>>(
            delta, u_bf, xdbl, A_log + (size_t)l * DI * NSTATE, Ach, xz,
            D_skip + (size_t)l * DI, yg_bf);

        // out_proj: [1024,2048] x [1024,2048]^T + resid -> out
        gemm_mfma<64, 2><<<dim3(1024 / 64, L / 128, 1), 256, 0, stream>>>(
            yg_bf, DI, wo, DI, out, D, D, DI, 0, nullptr, xin);
    }
}